// Round 1
// baseline (9.902 us; speedup 1.0000x reference)
//
#include <hip/hip_runtime.h>

#define FRAME_N 8
#define NPIX (180 * 320)

// Per-pixel closed-form solve of the reference's ADMM + CG:
//   mask m = (ce > 0), c = 1/8 - m
//   A = rho*I + m m^T + c c^T  (8x8, rank-2 + scaled identity)
//   A^{-1} v = (v - U S^{-1} U^T v) / rho,  U=[m c], S = rho*I2 + U^T U (2x2)
//   b0 = m.f, b1 = c.f ; atb = m*b0 + c*b1 ; x0 = [b0 x4, b1 x4]
//   x1 = A^{-1} atb ; out = A^{-1}(atb + rho*(x0 - x1))
// Noise term (5e-10) is ~1e-7 in the output, far below the 0.28 threshold -> skipped.
__global__ void __launch_bounds__(256) admm_video_kernel(
    const float* __restrict__ frames,
    const float* __restrict__ ce,
    const float* __restrict__ rho_p,
    float* __restrict__ out)
{
    int pix = blockIdx.x * blockDim.x + threadIdx.x;
    if (pix >= NPIX) return;

    const double rho = (double)rho_p[0];

    double f[FRAME_N], m[FRAME_N], c[FRAME_N];
#pragma unroll
    for (int t = 0; t < FRAME_N; ++t) {
        f[t] = (double)frames[t * NPIX + pix];
        float w = ce[t * NPIX + pix];
        m[t] = (w > 0.0f) ? 1.0 : 0.0;
        c[t] = 0.125 - m[t];
    }

    // b = Afun(mask, frames)
    double b0 = 0.0, b1 = 0.0;
#pragma unroll
    for (int t = 0; t < FRAME_N; ++t) {
        b0 += m[t] * f[t];
        b1 += c[t] * f[t];
    }

    // Gram matrix of U = [m c]
    double g00 = 0.0, g01 = 0.0, g11 = 0.0;
#pragma unroll
    for (int t = 0; t < FRAME_N; ++t) {
        g00 += m[t] * m[t];
        g01 += m[t] * c[t];
        g11 += c[t] * c[t];
    }
    const double s00 = rho + g00;
    const double s01 = g01;
    const double s11 = rho + g11;
    const double inv_det = 1.0 / (s00 * s11 - s01 * s01);
    const double inv_rho = 1.0 / rho;

    // atb = At(b) = m*b0 + c*b1
    double atb[FRAME_N];
#pragma unroll
    for (int t = 0; t < FRAME_N; ++t) atb[t] = m[t] * b0 + c[t] * b1;

    // x1 = A^{-1} atb
    double p0 = 0.0, p1 = 0.0;
#pragma unroll
    for (int t = 0; t < FRAME_N; ++t) { p0 += m[t] * atb[t]; p1 += c[t] * atb[t]; }
    double w0 = (s11 * p0 - s01 * p1) * inv_det;
    double w1 = (s00 * p1 - s01 * p0) * inv_det;
    double x1[FRAME_N];
#pragma unroll
    for (int t = 0; t < FRAME_N; ++t)
        x1[t] = (atb[t] - m[t] * w0 - c[t] * w1) * inv_rho;

    // v2 = atb + rho*(x0 - x1), x0 = repeat(b, 4)
    double v2[FRAME_N];
#pragma unroll
    for (int t = 0; t < FRAME_N; ++t) {
        double x0 = (t < 4) ? b0 : b1;
        v2[t] = atb[t] + rho * (x0 - x1[t]);
    }

    // x2 = A^{-1} v2
    p0 = 0.0; p1 = 0.0;
#pragma unroll
    for (int t = 0; t < FRAME_N; ++t) { p0 += m[t] * v2[t]; p1 += c[t] * v2[t]; }
    w0 = (s11 * p0 - s01 * p1) * inv_det;
    w1 = (s00 * p1 - s01 * p0) * inv_det;
#pragma unroll
    for (int t = 0; t < FRAME_N; ++t)
        out[t * NPIX + pix] = (float)((v2[t] - m[t] * w0 - c[t] * w1) * inv_rho);
}

extern "C" void kernel_launch(void* const* d_in, const int* in_sizes, int n_in,
                              void* d_out, int out_size, void* d_ws, size_t ws_size,
                              hipStream_t stream) {
    const float* frames = (const float*)d_in[0];
    const float* ce     = (const float*)d_in[1];
    const float* rho    = (const float*)d_in[2];
    float* out = (float*)d_out;

    const int threads = 256;
    const int blocks = (NPIX + threads - 1) / threads;
    admm_video_kernel<<<blocks, threads, 0, stream>>>(frames, ce, rho, out);
}

// Round 2
// 9.872 us; speedup vs baseline: 1.0031x; 1.0031x over previous
//
#include <hip/hip_runtime.h>

#define FRAME_N 8
#define NPIX (180 * 320)
#define NQ (NPIX / 4)

// Fully collapsed closed form of the reference ADMM+CG.
//   A = rho*I + U U^T,  U = [m c] (8x2), m = (ce>0), c = 1/8 - m
//   push-through: A^{-1} U = U S^{-1},  S = rho*I2 + G,  G = U^T U
//   x1 = U S^{-1} b ;  x2 = x0 + U S^{-1} (b - rho*a - U^T x0),  a = S^{-1} b
// Gram entries are closed-form in k = popcount(m):
//   g00 = k, g01 = -0.875k, g11 = 0.75k + 0.125
//   det(S) = rho^2 + rho(1.75k + 0.125) + 0.015625*k*(8-k)   (all-positive, stable)
// No 1/rho anywhere; the near-singular S direction at k=8 satisfies U q0 = 0,
// so its amplified error is annihilated in the output -> f32 is safe.
// Noise term (5e-10) perturbs output ~1e-7 -> skipped.
__global__ void __launch_bounds__(64) admm_video_kernel(
    const float4* __restrict__ frames,
    const float4* __restrict__ ce,
    const float* __restrict__ rho_p,
    float4* __restrict__ out)
{
    int q = blockIdx.x * blockDim.x + threadIdx.x;  // quad-pixel index
    if (q >= NQ) return;

    const float rho = rho_p[0];

    float4 f4[FRAME_N], w4[FRAME_N], o4[FRAME_N];
#pragma unroll
    for (int t = 0; t < FRAME_N; ++t) {
        f4[t] = frames[t * NQ + q];
        w4[t] = ce[t * NQ + q];
    }

    const float* fp = reinterpret_cast<const float*>(f4);
    const float* wp = reinterpret_cast<const float*>(w4);
    float* op = reinterpret_cast<float*>(o4);

#pragma unroll
    for (int p = 0; p < 4; ++p) {
        // gather this pixel's 8 frames + mask
        float sumf = 0.0f, b0 = 0.0f;
        int k = 0, k0 = 0;
        bool m[FRAME_N];
#pragma unroll
        for (int t = 0; t < FRAME_N; ++t) {
            float fv = fp[t * 4 + p];
            bool mv = wp[t * 4 + p] > 0.0f;
            m[t] = mv;
            sumf += fv;
            b0 += mv ? fv : 0.0f;
            k += mv ? 1 : 0;
            k0 += (mv && t < 4) ? 1 : 0;
        }
        const float b1 = 0.125f * sumf - b0;
        const float fk = (float)k;

        // S = rho*I + G, closed form in k
        const float s00 = rho + fk;
        const float s01 = -0.875f * fk;
        const float s11 = rho + 0.75f * fk + 0.125f;
        const float det = rho * rho + rho * (1.75f * fk + 0.125f)
                        + 0.015625f * fk * (8.0f - fk);
        const float invdet = 1.0f / det;

        // a = S^{-1} b
        const float a0 = (s11 * b0 - s01 * b1) * invdet;
        const float a1 = (s00 * b1 - s01 * b0) * invdet;

        // t = U^T x0, x0 = [b0 x4, b1 x4]
        const float k0f = (float)k0;
        const float k1f = fk - k0f;
        const float t0 = k0f * b0 + k1f * b1;
        const float t1 = 0.5f * (b0 + b1) - t0;

        // r = b - rho*a - t ; beta = S^{-1} r
        const float r0 = b0 - rho * a0 - t0;
        const float r1 = b1 - rho * a1 - t1;
        const float be0 = (s11 * r0 - s01 * r1) * invdet;
        const float be1 = (s00 * r1 - s01 * r0) * invdet;

        // out[t] = x0[t] + 0.125*be1 + m[t]*(be0 - be1)
        const float base = 0.125f * be1;
        const float dmb = be0 - be1;
#pragma unroll
        for (int t = 0; t < FRAME_N; ++t) {
            float x0 = (t < 4) ? b0 : b1;
            op[t * 4 + p] = x0 + base + (m[t] ? dmb : 0.0f);
        }
    }

#pragma unroll
    for (int t = 0; t < FRAME_N; ++t)
        out[t * NQ + q] = o4[t];
}

extern "C" void kernel_launch(void* const* d_in, const int* in_sizes, int n_in,
                              void* d_out, int out_size, void* d_ws, size_t ws_size,
                              hipStream_t stream) {
    const float4* frames = (const float4*)d_in[0];
    const float4* ce     = (const float4*)d_in[1];
    const float* rho     = (const float*)d_in[2];
    float4* out = (float4*)d_out;

    const int threads = 64;
    const int blocks = (NQ + threads - 1) / threads;  // 225
    admm_video_kernel<<<blocks, threads, 0, stream>>>(frames, ce, rho, out);
}